// Round 13
// baseline (206.483 us; speedup 1.0000x reference)
//
#include <hip/hip_runtime.h>
#include <hip/hip_bf16.h>
#include <stdint.h>

#define BB 2
#define NN 2048
#define CC 1024
#define HH 16
#define DD 64
#define C3 3072

typedef __attribute__((ext_vector_type(8))) short bf16x8;
typedef __attribute__((ext_vector_type(4))) short bf16x4;
typedef __attribute__((ext_vector_type(4))) float f32x4;
typedef __attribute__((ext_vector_type(16))) float f32x16;
typedef __attribute__((ext_vector_type(4))) unsigned short ushort4_t;

__device__ __forceinline__ unsigned short f2bf(float f) {
  union { float f; unsigned u; } v; v.f = f;
  unsigned r = v.u + 0x7FFFu + ((v.u >> 16) & 1u);
  return (unsigned short)(r >> 16);
}

#if __has_builtin(__builtin_amdgcn_exp2f)
#define EXP2(x) __builtin_amdgcn_exp2f(x)
#else
#define EXP2(x) exp2f(x)
#endif

// truncating pack of two f32 -> one VGPR holding {lo16=hi(a), hi16=hi(b)}
__device__ __forceinline__ unsigned pack_bf2(float a, float b) {
  union { float f; unsigned u; } ua, ub; ua.f = a; ub.f = b;
#if __has_builtin(__builtin_amdgcn_perm)
  return __builtin_amdgcn_perm(ub.u, ua.u, 0x07060302u);
#else
  return (ua.u >> 16) | (ub.u & 0xFFFF0000u);
#endif
}

// 0.125 (1/sqrt(D)) * log2(e): folded into Q so softmax is raw v_exp_f32 (2^x)
#define QSCALE 0.18033688f

// async global->LDS, 16B per lane; LDS dest must be wave-uniform base + lane*16
#define GLDS(g, l) __builtin_amdgcn_global_load_lds( \
    (const __attribute__((address_space(1))) void*)(g), \
    (__attribute__((address_space(3))) void*)(l), 16, 0, 0)

// ----------------------------------------- merged fp32->bf16 converts (3 bufs)
__global__ __launch_bounds__(256) void k_cvt(
    const float* __restrict__ x, const float* __restrict__ wq,
    const float* __restrict__ wp,
    unsigned short* __restrict__ xb, unsigned short* __restrict__ wqb,
    unsigned short* __restrict__ wpb)
{
  int blk = blockIdx.x;
  const float* s; unsigned short* d; int i;
  if (blk < 4096)      { s = x;  d = xb;  i = blk * 256 + threadIdx.x; }
  else if (blk < 7168) { s = wq; d = wqb; i = (blk - 4096) * 256 + threadIdx.x; }
  else                 { s = wp; d = wpb; i = (blk - 7168) * 256 + threadIdx.x; }
  float4 v = ((const float4*)s)[i];
  ushort4_t o;
  o.x = f2bf(v.x); o.y = f2bf(v.y); o.z = f2bf(v.z); o.w = f2bf(v.w);
  ((ushort4_t*)d)[i] = o;
}

// -------------------------------- GEMM1 fused: qkv = x@Wqkv^T + b, RoPE, pack
// v20: COUNTED-VMCNT 3-BUFFER PIPELINE (prefetch distance 2). qkv's compute
// phase (~200-400cy: 16 MFMA + 8 ds_read) is SHORTER than load latency
// (L2 ~200 / HBM ~900cy), so the old distance-1 + vmcnt(0)-drain barrier
// exposed ~300-500cy per iteration x 32 iters (MfmaUtil 16%, nothing
// saturated). Per iter: s_waitcnt vmcnt(4) (own tile landed; next tile's 4
// loads stay in flight ACROSS the raw s_barrier), stage tile t+2 into buf
// (t+2)%3, compute buf t%3. LDS 48KB (3x16KB) -> still 3 blocks/CU (the
// grid limit) so occupancy is unchanged. No sched_barrier pinning (v12's
// mistake). Hazard: buf b staged at iter b+1 (mod 3), after barrier b+1,
// whose readers (iter b) consumed their ds_reads before that barrier;
// vmcnt(4) at t retires exactly the stage issued at t-2. Last iter: vmcnt(0).
// T2 both-sides bank swizzle kept (conflicts 164K). Epilogue unchanged.
__global__ __launch_bounds__(256) void k_gemm_qkv(
    const unsigned short* __restrict__ A, const unsigned short* __restrict__ Bt,
    const float* __restrict__ bias,
    const float* __restrict__ cosb, const float* __restrict__ sinb,
    unsigned short* __restrict__ Qg, unsigned short* __restrict__ Kg,
    unsigned short* __restrict__ Vt)
{
  __shared__ __align__(16) unsigned short Sh[24576];  // 48KB: 3 staging bufs / epilogue
  const int tid  = threadIdx.x;
  const int lane = tid & 63;
  const int wave = tid >> 6;
  const int bm = blockIdx.y * 128;
  const int bn = blockIdx.x * 128;
  const int wm = (wave >> 1) * 64;
  const int wn = (wave & 1) * 64;
  const int frow = lane & 15;
  const int fks  = (((lane >> 4) ^ ((frow >> 1) & 3)) * 8);  // swizzled chunk
  const int K = 1024;
  const int NIT = K / 32;

  f32x4 acc[4][4] = {};

  const int row0 = tid >> 2, cc0 = tid & 3;
  const int row1 = row0 + 64;
  const int scc = (cc0 ^ ((row0 >> 1) & 3)) * 8;   // pre-swizzled source chunk
  const unsigned short* Arow0 = A  + (size_t)(bm + row0) * K + scc;
  const unsigned short* Arow1 = A  + (size_t)(bm + row1) * K + scc;
  const unsigned short* Brow0 = Bt + (size_t)(bn + row0) * K + scc;
  const unsigned short* Brow1 = Bt + (size_t)(bn + row1) * K + scc;

  // stage one BK=32 tile-pair (4 GLDS) into buffer bf
#define STAGEQ(bf, k1) do { \
    unsigned short* An = Sh + (bf) * 8192; \
    GLDS(Arow0 + (k1), An + (size_t)tid * 8); \
    GLDS(Brow0 + (k1), An + 4096 + (size_t)tid * 8); \
    GLDS(Arow1 + (k1), An + (size_t)(tid + 256) * 8); \
    GLDS(Brow1 + (k1), An + 4096 + (size_t)(tid + 256) * 8); \
  } while (0)

  // prologue: tiles 0,1 into buffers 0,1 (8 loads in flight)
  STAGEQ(0, 0);
  STAGEQ(1, 32);

  int bc = 0;   // compute buffer (it % 3)
  int bs = 2;   // stage buffer ((it+2) % 3)
  for (int it = 0; it < NIT; ++it) {
    if (it == NIT - 1) asm volatile("s_waitcnt vmcnt(0)" ::: "memory");
    else               asm volatile("s_waitcnt vmcnt(4)" ::: "memory");
    __builtin_amdgcn_s_barrier();

    if (it + 2 < NIT) STAGEQ(bs, (it + 2) * 32);

    const unsigned short* As = Sh + bc * 8192;
    const unsigned short* Bs = As + 4096;

    bf16x8 af[4], bfr[4];
#pragma unroll
    for (int t = 0; t < 4; ++t) {
      af[t]  = *(const bf16x8*)(As + (wm + t * 16 + frow) * 32 + fks);
      bfr[t] = *(const bf16x8*)(Bs + (wn + t * 16 + frow) * 32 + fks);
    }
#pragma unroll
    for (int mt = 0; mt < 4; ++mt)
#pragma unroll
      for (int nt = 0; nt < 4; ++nt)
        acc[mt][nt] = __builtin_amdgcn_mfma_f32_16x16x32_bf16(af[mt], bfr[nt], acc[mt][nt], 0, 0, 0);

    bc = (bc == 2) ? 0 : bc + 1;
    bs = (bs == 2) ? 0 : bs + 1;
  }
#undef STAGEQ
  __syncthreads();   // full drain; staging LDS now reusable for epilogue

  const int er0  = (lane >> 4) * 4;
  const int ecol = lane & 15;
  const int region = bn >> 10;                 // wave-uniform: 0=Q,1=K,2=V
  const int gcol0 = bn + wn;                   // 64-aligned -> one head
  const int h  = (gcol0 >> 6) & 15;
  const int rowg0 = bm + wm;                   // wave-uniform
  const int b  = rowg0 >> 11;
  const int n0 = rowg0 & (NN - 1);
  unsigned short* wt = Sh + wave * 4096;       // 64x64 wave-private tile

#pragma unroll
  for (int nt = 0; nt < 4; ++nt) {
    const int c64 = nt * 16 + ecol;            // d within head
    const float bv = bias[gcol0 + c64];
    const int ii  = c64 >> 1;
#pragma unroll
    for (int mt = 0; mt < 4; ++mt)
#pragma unroll
      for (int r = 0; r < 4; ++r) {
        const int ml = mt * 16 + er0 + r;      // row within wave tile
        const int n  = n0 + ml;
        float v = acc[mt][nt][r] + bv;
        float vp = __shfl_xor(v, 1, 64);       // pair partner (d^1)
        if (region == 2) {
          wt[c64 * 64 + ((((ml >> 3) ^ (c64 & 7)) << 3) | (ml & 7))] = f2bf(v);
        } else {
          float cth = cosb[n * 32 + ii], sth = sinb[n * 32 + ii];
          float ov = (c64 & 1) ? (vp * sth + v * cth)
                               : (v * cth - vp * sth);
          if (region == 0) ov *= QSCALE;
          wt[ml * 64 + ((((c64 >> 3) ^ (ml & 7)) << 3) | (c64 & 7))] = f2bf(ov);
        }
      }
  }

  const int rr = lane >> 3, cc = lane & 7;
  if (region == 2) {
    // pi-permuted store: stored[col] = V[kv = P(col)], P = swap bits 2,3.
    unsigned short* dst = Vt + (size_t)(b * HH + h) * DD * NN + n0;
    const int q8a = (cc >> 1) * 2;
    const int q8b = q8a + 1;
    const int half = (cc & 1) * 4;
#pragma unroll
    for (int it = 0; it < 8; ++it) {
      int dl = it * 8 + rr;
      union { bf16x4 h[2]; bf16x8 w; } vv;
      vv.h[0] = *(const bf16x4*)(wt + dl * 64 + ((q8a ^ (dl & 7)) << 3) + half);
      vv.h[1] = *(const bf16x4*)(wt + dl * 64 + ((q8b ^ (dl & 7)) << 3) + half);
      *(bf16x8*)(dst + (size_t)dl * NN + cc * 8) = vv.w;
    }
  } else {
    unsigned short* dqk = ((region == 0) ? Qg : Kg) +
                          ((size_t)(b * HH + h) * NN + n0) * DD;
#pragma unroll
    for (int it = 0; it < 8; ++it) {
      int ml = it * 8 + rr;
      bf16x8 vv = *(const bf16x8*)(wt + ml * 64 + ((cc ^ (ml & 7)) << 3));
      *(bf16x8*)(dqk + (size_t)ml * DD + cc * 8) = vv;
    }
  }
}

// ----------------------------------------------------- flash attention v19
// (unchanged -- best known). 256 q/block, 512 thr/8 waves, grid 256 with
// XCD swizzle; KVBLK=128 as two 64-kv sub-tiles/span, 4+4 bufs, 64KB LDS.
__global__ __launch_bounds__(512) void k_attn(
    const unsigned short* __restrict__ Qg, const unsigned short* __restrict__ Kg,
    const unsigned short* __restrict__ Vtg, unsigned short* __restrict__ Og)
{
  __shared__ __align__(16) unsigned short Ks[4][64 * 64];
  __shared__ __align__(16) unsigned short Vs[4][64 * 64];

  const int tid  = threadIdx.x;
  const int lane = tid & 63;
  const int wave = tid >> 6;                    // 0..7
  const int wid  = (blockIdx.x & 7) * 32 + (blockIdx.x >> 3);  // XCD-clustered
  const int bh = wid >> 3;                      // 0..31
  const int qt = wid & 7;                       // 0..7
  const int q0 = qt * 256 + wave * 32;
  const int l31 = lane & 31;
  const int hi  = lane >> 5;
  const int s7  = l31 & 7;

  const unsigned short* Qb = Qg  + (size_t)bh * NN * DD;
  const unsigned short* Kb = Kg  + (size_t)bh * NN * DD;
  const unsigned short* Vb = Vtg + (size_t)bh * DD * NN;

  // one byte-offset table for ALL LDS reads: row l31, 16B slot (2i+hi)^s7
  int soffB[4];
#pragma unroll
  for (int i = 0; i < 4; ++i)
    soffB[i] = (l31 * 64 + (((2 * i + hi) ^ s7) << 3)) * 2;

  // Q fragments (B-operand of 32x32x16: n = l31 = q, k = hi*8+j = d)
  bf16x8 qf[4];
#pragma unroll
  for (int dc = 0; dc < 4; ++dc)
    qf[dc] = *(const bf16x8*)(Qb + (size_t)(q0 + l31) * DD + dc * 16 + hi * 8);

  bf16x8 ones;
#pragma unroll
  for (int i = 0; i < 8; ++i) ones[i] = (short)0x3F80;
  const f32x16 zero16 = {};   // loop-invariant C for first MFMA of each chain

  f32x16 oacc[2] = {};
  f32x16 lacc = {};

  const int row0 = tid >> 3, cc0 = tid & 7;     // row0 0..63 (512 threads)
  const int sw0 = (cc0 ^ (row0 & 7)) * 8;

  // stage one 64x64 K sub-tile + one 64x64 V sub-tile (2 GLDS, 512 lanes)
#define STAGE64(bf, j) do { \
    GLDS(Kb + (size_t)((j) + row0) * DD + sw0, Ks[bf] + (size_t)tid * 8); \
    GLDS(Vb + (size_t)row0 * NN + (j) + sw0,   Vs[bf] + (size_t)tid * 8); \
  } while (0)

  // prologue: both sub-tiles of kv-tile 0 into buffers 0,1
  STAGE64(0, 0);
  STAGE64(1, 64);

  const int NT = NN / 128;          // 16 barrier spans
#pragma unroll 2
  for (int t = 0; t < NT; ++t) {
    const int p = t & 1;            // tile t lives in bufs {2p, 2p+1}
    __syncthreads();                // drains vmcnt+lgkmcnt: tile t ready

    if (t + 1 < NT) {               // stage tile t+1 into bufs {2(1-p), ...+1}
      STAGE64(2 * (1 - p),     (t + 1) * 128);
      STAGE64(2 * (1 - p) + 1, (t + 1) * 128 + 64);
    }

#pragma unroll
    for (int sub = 0; sub < 2; ++sub) {
      const char* KsB = (const char*)Ks[2 * p + sub];
      const char* VsB = (const char*)Vs[2 * p + sub];

      // S^T = K Q^T : A = K (m=kv), B = Q (n=q); 2 kv-halves x 4 d-chunks
      f32x16 sacc[2];
      __builtin_amdgcn_s_setprio(1);
#pragma unroll
      for (int T = 0; T < 2; ++T) {
        bf16x8 kf0 = *(const bf16x8*)(KsB + T * 4096 + soffB[0]);
        sacc[T] = __builtin_amdgcn_mfma_f32_32x32x16_bf16(kf0, qf[0], zero16, 0, 0, 0);
#pragma unroll
        for (int dc = 1; dc < 4; ++dc) {
          bf16x8 kf = *(const bf16x8*)(KsB + T * 4096 + soffB[dc]);
          sacc[T] = __builtin_amdgcn_mfma_f32_32x32x16_bf16(kf, qf[dc], sacc[T], 0, 0, 0);
        }
      }
      __builtin_amdgcn_s_setprio(0);

      // per kv-half: exp -> pack (pi-order, no swaps) -> PV + l MFMAs
#pragma unroll
      for (int T = 0; T < 2; ++T) {
        unsigned pk[8];
#pragma unroll
        for (int jj = 0; jj < 8; ++jj) {
          float e0 = EXP2(sacc[T][2 * jj]);
          float e1 = EXP2(sacc[T][2 * jj + 1]);
          pk[jj] = pack_bf2(e0, e1);
        }
        union { unsigned u[4]; bf16x8 v; } fa, fb;
        fa.u[0] = pk[0]; fa.u[1] = pk[1]; fa.u[2] = pk[2]; fa.u[3] = pk[3];
        fb.u[0] = pk[4]; fb.u[1] = pk[5]; fb.u[2] = pk[6]; fb.u[3] = pk[7];
        // fa covers kv T*32 + g(hi,j); fb covers kv T*32 + 16 + g(hi,j)
        // Vs pi-order: frag (T,c') = b128 at slot 4T+2c'+hi -> soffB[2T+c']
        __builtin_amdgcn_s_setprio(1);
#pragma unroll
        for (int dt = 0; dt < 2; ++dt) {
          bf16x8 v0 = *(const bf16x8*)(VsB + dt * 4096 + soffB[2 * T + 0]);
          bf16x8 v1 = *(const bf16x8*)(VsB + dt * 4096 + soffB[2 * T + 1]);
          oacc[dt] = __builtin_amdgcn_mfma_f32_32x32x16_bf16(fa.v, v0, oacc[dt], 0, 0, 0);
          oacc[dt] = __builtin_amdgcn_mfma_f32_32x32x16_bf16(fb.v, v1, oacc[dt], 0, 0, 0);
        }
        lacc = __builtin_amdgcn_mfma_f32_32x32x16_bf16(fa.v, ones, lacc, 0, 0, 0);
        lacc = __builtin_amdgcn_mfma_f32_32x32x16_bf16(fb.v, ones, lacc, 0, 0, 0);
        __builtin_amdgcn_s_setprio(0);
      }
    }
  }
#undef STAGE64

  // epilogue: lacc[r] = l[q=crow(r,hi)] (uniform in n). O row q, col d = l31.
  const int b = bh >> 4;
  const int h = bh & 15;
#pragma unroll
  for (int r = 0; r < 16; ++r) {
    const int qr = (r & 3) + 8 * (r >> 2) + 4 * hi;
    const float linv = 1.0f / lacc[r];
    unsigned short* orow = Og + (size_t)(b * NN + q0 + qr) * CC + h * DD + l31;
    orow[0]  = f2bf(oacc[0][r] * linv);
    orow[32] = f2bf(oacc[1][r] * linv);
  }
}

// ------------------------------- GEMM2: out = aob @ Wproj^T + b (fp32 out)
// v18 (unchanged): span-doubled BK=64 (two independent 32-K sub-tiles, 4
// staging buffers, 48KB LDS), T2 both-sides swizzle.
__global__ __launch_bounds__(256) void k_gemm_proj(
    const unsigned short* __restrict__ A, const unsigned short* __restrict__ Bt,
    const float* __restrict__ bias, float* __restrict__ Co)
{
  __shared__ __align__(16) unsigned short As[4][64 * 32];
  __shared__ __align__(16) unsigned short Bs[4][128 * 32];
  const int tid  = threadIdx.x;
  const int lane = tid & 63;
  const int wave = tid >> 6;
  const int bm = blockIdx.y * 64;
  const int bn = blockIdx.x * 128;
  const int wm = (wave >> 1) * 32;
  const int wn = (wave & 1) * 64;
  const int frow = lane & 15;
  const int fks  = (((lane >> 4) ^ ((frow >> 1) & 3)) * 8);  // swizzled chunk
  const int K = 1024;

  f32x4 acc[2][4] = {};

  const int row0 = tid >> 2, cc0 = tid & 3;
  const int scc = (cc0 ^ ((row0 >> 1) & 3)) * 8;   // pre-swizzled source chunk
  const unsigned short* Arow  = A  + (size_t)(bm + row0) * K + scc;
  const unsigned short* Brow0 = Bt + (size_t)(bn + row0) * K + scc;
  const unsigned short* Brow1 = Bt + (size_t)(bn + row0 + 64) * K + scc;

  // stage one 32-K sub-tile (3 GLDS)
#define STAGEP(bf, k1) do { \
    GLDS(Arow  + (k1), As[bf] + (size_t)tid * 8); \
    GLDS(Brow0 + (k1), Bs[bf] + (size_t)tid * 8); \
    GLDS(Brow1 + (k1), Bs[bf] + (size_t)(tid + 256) * 8); \
  } while (0)

  // prologue: both sub-tiles of span 0 into buffers 0,1
  STAGEP(0, 0);
  STAGEP(1, 32);

  const int NT = K / 64;            // 16 barrier spans
  for (int t = 0; t < NT; ++t) {
    const int p = t & 1;            // span t lives in bufs {2p, 2p+1}
    __syncthreads();                // span t ready

    if (t + 1 < NT) {               // stage span t+1 into the other pair
      STAGEP(2 * (1 - p),     (t + 1) * 64);
      STAGEP(2 * (1 - p) + 1, (t + 1) * 64 + 32);
    }

#pragma unroll
    for (int sub = 0; sub < 2; ++sub) {
      const unsigned short* Asb = As[2 * p + sub];
      const unsigned short* Bsb = Bs[2 * p + sub];
      bf16x8 af[2], bfr[4];
#pragma unroll
      for (int q = 0; q < 2; ++q)
        af[q] = *(const bf16x8*)(Asb + (wm + q * 16 + frow) * 32 + fks);
#pragma unroll
      for (int q = 0; q < 4; ++q)
        bfr[q] = *(const bf16x8*)(Bsb + (wn + q * 16 + frow) * 32 + fks);
#pragma unroll
      for (int mt = 0; mt < 2; ++mt)
#pragma unroll
        for (int nt = 0; nt < 4; ++nt)
          acc[mt][nt] = __builtin_amdgcn_mfma_f32_16x16x32_bf16(af[mt], bfr[nt], acc[mt][nt], 0, 0, 0);
    }
  }
#undef STAGEP

  const int er0  = (lane >> 4) * 4;
  const int ecol = lane & 15;
#pragma unroll
  for (int nt = 0; nt < 4; ++nt) {
    int col = bn + wn + nt * 16 + ecol;
    float bv = bias[col];
#pragma unroll
    for (int mt = 0; mt < 2; ++mt)
#pragma unroll
      for (int r = 0; r < 4; ++r) {
        int rowg = bm + wm + mt * 16 + er0 + r;
        Co[(size_t)rowg * CC + col] = acc[mt][nt][r] + bv;
      }
  }
}

// ---------------------------------------------------------------- launcher
extern "C" void kernel_launch(void* const* d_in, const int* in_sizes, int n_in,
                              void* d_out, int out_size, void* d_ws, size_t ws_size,
                              hipStream_t stream)
{
  const float* x      = (const float*)d_in[0];
  const float* w_qkv  = (const float*)d_in[1];
  const float* b_qkv  = (const float*)d_in[2];
  const float* w_proj = (const float*)d_in[3];
  const float* b_proj = (const float*)d_in[4];
  const float* fcos   = (const float*)d_in[5];
  const float* fsin   = (const float*)d_in[6];
  float* out = (float*)d_out;

  char* ws = (char*)d_ws;
  unsigned short* xb     = (unsigned short*)(ws);              //  8 MB
  unsigned short* wqkvb  = (unsigned short*)(ws + 8388608);    //  6 MB
  unsigned short* wprojb = (unsigned short*)(ws + 14680064);   //  2 MB
  unsigned short* Qb     = (unsigned short*)(ws + 16777216);   //  8 MB
  unsigned short* Kb     = (unsigned short*)(ws + 25165824);   //  8 MB
  unsigned short* Vtb    = (unsigned short*)(ws + 33554432);   //  8 MB
  unsigned short* aob    = (unsigned short*)(ws + 41943040);   //  8 MB

  k_cvt<<<8192, 256, 0, stream>>>(x, w_qkv, w_proj, xb, wqkvb, wprojb);

  k_gemm_qkv<<<dim3(24, 32), 256, 0, stream>>>(xb, wqkvb, b_qkv, fcos, fsin,
                                               Qb, Kb, Vtb);

  k_attn<<<256, 512, 0, stream>>>(Qb, Kb, Vtb, aob);

  k_gemm_proj<<<dim3(8, 64), 256, 0, stream>>>(aob, wprojb, b_proj, out);
}

// Round 14
// 196.460 us; speedup vs baseline: 1.0510x; 1.0510x over previous
//
#include <hip/hip_runtime.h>
#include <hip/hip_bf16.h>
#include <stdint.h>

#define BB 2
#define NN 2048
#define CC 1024
#define HH 16
#define DD 64
#define C3 3072

typedef __attribute__((ext_vector_type(8))) short bf16x8;
typedef __attribute__((ext_vector_type(4))) short bf16x4;
typedef __attribute__((ext_vector_type(4))) float f32x4;
typedef __attribute__((ext_vector_type(16))) float f32x16;
typedef __attribute__((ext_vector_type(4))) unsigned short ushort4_t;

__device__ __forceinline__ unsigned short f2bf(float f) {
  union { float f; unsigned u; } v; v.f = f;
  unsigned r = v.u + 0x7FFFu + ((v.u >> 16) & 1u);
  return (unsigned short)(r >> 16);
}

#if __has_builtin(__builtin_amdgcn_exp2f)
#define EXP2(x) __builtin_amdgcn_exp2f(x)
#else
#define EXP2(x) exp2f(x)
#endif

// truncating pack of two f32 -> one VGPR holding {lo16=hi(a), hi16=hi(b)}
__device__ __forceinline__ unsigned pack_bf2(float a, float b) {
  union { float f; unsigned u; } ua, ub; ua.f = a; ub.f = b;
#if __has_builtin(__builtin_amdgcn_perm)
  return __builtin_amdgcn_perm(ub.u, ua.u, 0x07060302u);
#else
  return (ua.u >> 16) | (ub.u & 0xFFFF0000u);
#endif
}

// 0.125 (1/sqrt(D)) * log2(e): folded into Q so softmax is raw v_exp_f32 (2^x)
#define QSCALE 0.18033688f

// async global->LDS, 16B per lane; LDS dest must be wave-uniform base + lane*16
#define GLDS(g, l) __builtin_amdgcn_global_load_lds( \
    (const __attribute__((address_space(1))) void*)(g), \
    (__attribute__((address_space(3))) void*)(l), 16, 0, 0)

// ----------------------------------------- merged fp32->bf16 converts (3 bufs)
__global__ __launch_bounds__(256) void k_cvt(
    const float* __restrict__ x, const float* __restrict__ wq,
    const float* __restrict__ wp,
    unsigned short* __restrict__ xb, unsigned short* __restrict__ wqb,
    unsigned short* __restrict__ wpb)
{
  int blk = blockIdx.x;
  const float* s; unsigned short* d; int i;
  if (blk < 4096)      { s = x;  d = xb;  i = blk * 256 + threadIdx.x; }
  else if (blk < 7168) { s = wq; d = wqb; i = (blk - 4096) * 256 + threadIdx.x; }
  else                 { s = wp; d = wpb; i = (blk - 7168) * 256 + threadIdx.x; }
  float4 v = ((const float4*)s)[i];
  ushort4_t o;
  o.x = f2bf(v.x); o.y = f2bf(v.y); o.z = f2bf(v.z); o.w = f2bf(v.w);
  ((ushort4_t*)d)[i] = o;
}

// -------------------------------- GEMM1 fused: qkv = x@Wqkv^T + b, RoPE, pack
// v19 form restored EXACTLY (v20's 48KB 3-buffer pipeline dropped qkv from
// 3->2 blocks/CU: LDS >32KB is an occupancy cliff at grid 768). BK=32,
// 2 buffers, one __syncthreads/iter, T2 both-sides bank swizzle (conflicts
// 164K). Epilogue: RoPE in registers, wave-private LDS tile, Region V staged
// transposed with PI-PERMUTED kv order.
__global__ __launch_bounds__(256) void k_gemm_qkv(
    const unsigned short* __restrict__ A, const unsigned short* __restrict__ Bt,
    const float* __restrict__ bias,
    const float* __restrict__ cosb, const float* __restrict__ sinb,
    unsigned short* __restrict__ Qg, unsigned short* __restrict__ Kg,
    unsigned short* __restrict__ Vt)
{
  __shared__ __align__(16) unsigned short Sh[16384];  // 32KB: 2x(As+Bs) / epilogue
  const int tid  = threadIdx.x;
  const int lane = tid & 63;
  const int wave = tid >> 6;
  const int bm = blockIdx.y * 128;
  const int bn = blockIdx.x * 128;
  const int wm = (wave >> 1) * 64;
  const int wn = (wave & 1) * 64;
  const int frow = lane & 15;
  const int fks  = (((lane >> 4) ^ ((frow >> 1) & 3)) * 8);  // swizzled chunk
  const int K = 1024;
  const int NIT = K / 32;

  f32x4 acc[4][4] = {};

  const int row0 = tid >> 2, cc0 = tid & 3;
  const int row1 = row0 + 64;
  const int scc = (cc0 ^ ((row0 >> 1) & 3)) * 8;   // pre-swizzled source chunk
  const unsigned short* Arow0 = A  + (size_t)(bm + row0) * K + scc;
  const unsigned short* Arow1 = A  + (size_t)(bm + row1) * K + scc;
  const unsigned short* Brow0 = Bt + (size_t)(bn + row0) * K + scc;
  const unsigned short* Brow1 = Bt + (size_t)(bn + row1) * K + scc;

  GLDS(Arow0, Sh + (size_t)tid * 8);
  GLDS(Brow0, Sh + 4096 + (size_t)tid * 8);
  GLDS(Arow1, Sh + (size_t)(tid + 256) * 8);
  GLDS(Brow1, Sh + 4096 + (size_t)(tid + 256) * 8);

  for (int it = 0; it < NIT; ++it) {
    const int p = it & 1;
    const unsigned short* As = Sh + p * 8192;
    const unsigned short* Bs = As + 4096;
    __syncthreads();

    if (it + 1 < NIT) {
      const int k1 = (it + 1) * 32;
      unsigned short* An = Sh + (1 - p) * 8192;
      GLDS(Arow0 + k1, An + (size_t)tid * 8);
      GLDS(Brow0 + k1, An + 4096 + (size_t)tid * 8);
      GLDS(Arow1 + k1, An + (size_t)(tid + 256) * 8);
      GLDS(Brow1 + k1, An + 4096 + (size_t)(tid + 256) * 8);
    }

    bf16x8 af[4], bfr[4];
#pragma unroll
    for (int t = 0; t < 4; ++t) {
      af[t]  = *(const bf16x8*)(As + (wm + t * 16 + frow) * 32 + fks);
      bfr[t] = *(const bf16x8*)(Bs + (wn + t * 16 + frow) * 32 + fks);
    }
#pragma unroll
    for (int mt = 0; mt < 4; ++mt)
#pragma unroll
      for (int nt = 0; nt < 4; ++nt)
        acc[mt][nt] = __builtin_amdgcn_mfma_f32_16x16x32_bf16(af[mt], bfr[nt], acc[mt][nt], 0, 0, 0);
  }
  __syncthreads();   // staging LDS now reusable for epilogue

  const int er0  = (lane >> 4) * 4;
  const int ecol = lane & 15;
  const int region = bn >> 10;                 // wave-uniform: 0=Q,1=K,2=V
  const int gcol0 = bn + wn;                   // 64-aligned -> one head
  const int h  = (gcol0 >> 6) & 15;
  const int rowg0 = bm + wm;                   // wave-uniform
  const int b  = rowg0 >> 11;
  const int n0 = rowg0 & (NN - 1);
  unsigned short* wt = Sh + wave * 4096;       // 64x64 wave-private tile

#pragma unroll
  for (int nt = 0; nt < 4; ++nt) {
    const int c64 = nt * 16 + ecol;            // d within head
    const float bv = bias[gcol0 + c64];
    const int ii  = c64 >> 1;
#pragma unroll
    for (int mt = 0; mt < 4; ++mt)
#pragma unroll
      for (int r = 0; r < 4; ++r) {
        const int ml = mt * 16 + er0 + r;      // row within wave tile
        const int n  = n0 + ml;
        float v = acc[mt][nt][r] + bv;
        float vp = __shfl_xor(v, 1, 64);       // pair partner (d^1)
        if (region == 2) {
          wt[c64 * 64 + ((((ml >> 3) ^ (c64 & 7)) << 3) | (ml & 7))] = f2bf(v);
        } else {
          float cth = cosb[n * 32 + ii], sth = sinb[n * 32 + ii];
          float ov = (c64 & 1) ? (vp * sth + v * cth)
                               : (v * cth - vp * sth);
          if (region == 0) ov *= QSCALE;
          wt[ml * 64 + ((((c64 >> 3) ^ (ml & 7)) << 3) | (c64 & 7))] = f2bf(ov);
        }
      }
  }

  const int rr = lane >> 3, cc = lane & 7;
  if (region == 2) {
    // pi-permuted store: stored[col] = V[kv = P(col)], P = swap bits 2,3.
    unsigned short* dst = Vt + (size_t)(b * HH + h) * DD * NN + n0;
    const int q8a = (cc >> 1) * 2;
    const int q8b = q8a + 1;
    const int half = (cc & 1) * 4;
#pragma unroll
    for (int it = 0; it < 8; ++it) {
      int dl = it * 8 + rr;
      union { bf16x4 h[2]; bf16x8 w; } vv;
      vv.h[0] = *(const bf16x4*)(wt + dl * 64 + ((q8a ^ (dl & 7)) << 3) + half);
      vv.h[1] = *(const bf16x4*)(wt + dl * 64 + ((q8b ^ (dl & 7)) << 3) + half);
      *(bf16x8*)(dst + (size_t)dl * NN + cc * 8) = vv.w;
    }
  } else {
    unsigned short* dqk = ((region == 0) ? Qg : Kg) +
                          ((size_t)(b * HH + h) * NN + n0) * DD;
#pragma unroll
    for (int it = 0; it < 8; ++it) {
      int ml = it * 8 + rr;
      bf16x8 vv = *(const bf16x8*)(wt + ml * 64 + ((cc ^ (ml & 7)) << 3));
      *(bf16x8*)(dqk + (size_t)ml * DD + cc * 8) = vv;
    }
  }
}

// ----------------------------------------------------- flash attention v21
// v19 geometry (256 q/block, 512 thr/8 waves, grid 256, XCD swizzle,
// KVBLK=128 as two 64-kv sub-tiles/span) + DEPTH-2 COUNTED-VMCNT pipeline:
// since v19, attn runs 1 block/CU (grid-limited) -- no co-resident block
// hides the per-span vmcnt(0) drain anymore (this is the regime v12 lacked).
// 6 buffers (3 kv-tile pairs, 96KB: free -- LDS allows 1 block either way).
// Per span: s_waitcnt vmcnt(4) (own tile's 4 GLDS landed; next tile's 4 stay
// in flight ACROSS the raw s_barrier), stage tile t+2 into pair (t+2)%3,
// compute pair t%3. Hazard: pair b's readers (span b-1 mod) finish before
// barrier; vmcnt(4) at span t retires tile t in-order (Q-frag loads retire
// first, conservatively covered). Last span: vmcnt(0). v20 validated this
// exact pattern's correctness (its regression was qkv occupancy, N/A here).
__global__ __launch_bounds__(512) void k_attn(
    const unsigned short* __restrict__ Qg, const unsigned short* __restrict__ Kg,
    const unsigned short* __restrict__ Vtg, unsigned short* __restrict__ Og)
{
  __shared__ __align__(16) unsigned short Ks[6][64 * 64];
  __shared__ __align__(16) unsigned short Vs[6][64 * 64];

  const int tid  = threadIdx.x;
  const int lane = tid & 63;
  const int wave = tid >> 6;                    // 0..7
  const int wid  = (blockIdx.x & 7) * 32 + (blockIdx.x >> 3);  // XCD-clustered
  const int bh = wid >> 3;                      // 0..31
  const int qt = wid & 7;                       // 0..7
  const int q0 = qt * 256 + wave * 32;
  const int l31 = lane & 31;
  const int hi  = lane >> 5;
  const int s7  = l31 & 7;

  const unsigned short* Qb = Qg  + (size_t)bh * NN * DD;
  const unsigned short* Kb = Kg  + (size_t)bh * NN * DD;
  const unsigned short* Vb = Vtg + (size_t)bh * DD * NN;

  // one byte-offset table for ALL LDS reads: row l31, 16B slot (2i+hi)^s7
  int soffB[4];
#pragma unroll
  for (int i = 0; i < 4; ++i)
    soffB[i] = (l31 * 64 + (((2 * i + hi) ^ s7) << 3)) * 2;

  // Q fragments (B-operand of 32x32x16: n = l31 = q, k = hi*8+j = d)
  bf16x8 qf[4];
#pragma unroll
  for (int dc = 0; dc < 4; ++dc)
    qf[dc] = *(const bf16x8*)(Qb + (size_t)(q0 + l31) * DD + dc * 16 + hi * 8);

  bf16x8 ones;
#pragma unroll
  for (int i = 0; i < 8; ++i) ones[i] = (short)0x3F80;
  const f32x16 zero16 = {};   // loop-invariant C for first MFMA of each chain

  f32x16 oacc[2] = {};
  f32x16 lacc = {};

  const int row0 = tid >> 3, cc0 = tid & 7;     // row0 0..63 (512 threads)
  const int sw0 = (cc0 ^ (row0 & 7)) * 8;

  // stage one 64x64 K sub-tile + one 64x64 V sub-tile (2 GLDS, 512 lanes)
#define STAGE64(bf, j) do { \
    GLDS(Kb + (size_t)((j) + row0) * DD + sw0, Ks[bf] + (size_t)tid * 8); \
    GLDS(Vb + (size_t)row0 * NN + (j) + sw0,   Vs[bf] + (size_t)tid * 8); \
  } while (0)

  // prologue: tiles 0,1 into pairs 0,1 (8 loads in flight per thread)
  STAGE64(0, 0);
  STAGE64(1, 64);
  STAGE64(2, 128);
  STAGE64(3, 192);

  int prc = 0;   // compute pair (t % 3)
  int prs = 2;   // stage pair ((t+2) % 3)
  const int NT = NN / 128;          // 16 barrier spans

  for (int t = 0; t < NT; ++t) {
    if (t == NT - 1) asm volatile("s_waitcnt vmcnt(0)" ::: "memory");
    else             asm volatile("s_waitcnt vmcnt(4)" ::: "memory");
    __builtin_amdgcn_s_barrier();

    if (t + 2 < NT) {               // stage tile t+2 into pair (t+2)%3
      STAGE64(2 * prs,     (t + 2) * 128);
      STAGE64(2 * prs + 1, (t + 2) * 128 + 64);
    }

#pragma unroll
    for (int sub = 0; sub < 2; ++sub) {
      const char* KsB = (const char*)Ks[2 * prc + sub];
      const char* VsB = (const char*)Vs[2 * prc + sub];

      // S^T = K Q^T : A = K (m=kv), B = Q (n=q); 2 kv-halves x 4 d-chunks
      f32x16 sacc[2];
      __builtin_amdgcn_s_setprio(1);
#pragma unroll
      for (int T = 0; T < 2; ++T) {
        bf16x8 kf0 = *(const bf16x8*)(KsB + T * 4096 + soffB[0]);
        sacc[T] = __builtin_amdgcn_mfma_f32_32x32x16_bf16(kf0, qf[0], zero16, 0, 0, 0);
#pragma unroll
        for (int dc = 1; dc < 4; ++dc) {
          bf16x8 kf = *(const bf16x8*)(KsB + T * 4096 + soffB[dc]);
          sacc[T] = __builtin_amdgcn_mfma_f32_32x32x16_bf16(kf, qf[dc], sacc[T], 0, 0, 0);
        }
      }
      __builtin_amdgcn_s_setprio(0);

      // per kv-half: exp -> pack (pi-order, no swaps) -> PV + l MFMAs
#pragma unroll
      for (int T = 0; T < 2; ++T) {
        unsigned pk[8];
#pragma unroll
        for (int jj = 0; jj < 8; ++jj) {
          float e0 = EXP2(sacc[T][2 * jj]);
          float e1 = EXP2(sacc[T][2 * jj + 1]);
          pk[jj] = pack_bf2(e0, e1);
        }
        union { unsigned u[4]; bf16x8 v; } fa, fb;
        fa.u[0] = pk[0]; fa.u[1] = pk[1]; fa.u[2] = pk[2]; fa.u[3] = pk[3];
        fb.u[0] = pk[4]; fb.u[1] = pk[5]; fb.u[2] = pk[6]; fb.u[3] = pk[7];
        // fa covers kv T*32 + g(hi,j); fb covers kv T*32 + 16 + g(hi,j)
        // Vs pi-order: frag (T,c') = b128 at slot 4T+2c'+hi -> soffB[2T+c']
        __builtin_amdgcn_s_setprio(1);
#pragma unroll
        for (int dt = 0; dt < 2; ++dt) {
          bf16x8 v0 = *(const bf16x8*)(VsB + dt * 4096 + soffB[2 * T + 0]);
          bf16x8 v1 = *(const bf16x8*)(VsB + dt * 4096 + soffB[2 * T + 1]);
          oacc[dt] = __builtin_amdgcn_mfma_f32_32x32x16_bf16(fa.v, v0, oacc[dt], 0, 0, 0);
          oacc[dt] = __builtin_amdgcn_mfma_f32_32x32x16_bf16(fb.v, v1, oacc[dt], 0, 0, 0);
        }
        lacc = __builtin_amdgcn_mfma_f32_32x32x16_bf16(fa.v, ones, lacc, 0, 0, 0);
        lacc = __builtin_amdgcn_mfma_f32_32x32x16_bf16(fb.v, ones, lacc, 0, 0, 0);
        __builtin_amdgcn_s_setprio(0);
      }
    }

    prc = (prc == 2) ? 0 : prc + 1;
    prs = (prs == 2) ? 0 : prs + 1;
  }
#undef STAGE64

  // epilogue: lacc[r] = l[q=crow(r,hi)] (uniform in n). O row q, col d = l31.
  const int b = bh >> 4;
  const int h = bh & 15;
#pragma unroll
  for (int r = 0; r < 16; ++r) {
    const int qr = (r & 3) + 8 * (r >> 2) + 4 * hi;
    const float linv = 1.0f / lacc[r];
    unsigned short* orow = Og + (size_t)(b * NN + q0 + qr) * CC + h * DD + l31;
    orow[0]  = f2bf(oacc[0][r] * linv);
    orow[32] = f2bf(oacc[1][r] * linv);
  }
}

// ------------------------------- GEMM2: out = aob @ Wproj^T + b (fp32 out)
// v18 (unchanged): span-doubled BK=64 (two independent 32-K sub-tiles, 4
// staging buffers, 48KB LDS), T2 both-sides swizzle.
__global__ __launch_bounds__(256) void k_gemm_proj(
    const unsigned short* __restrict__ A, const unsigned short* __restrict__ Bt,
    const float* __restrict__ bias, float* __restrict__ Co)
{
  __shared__ __align__(16) unsigned short As[4][64 * 32];
  __shared__ __align__(16) unsigned short Bs[4][128 * 32];
  const int tid  = threadIdx.x;
  const int lane = tid & 63;
  const int wave = tid >> 6;
  const int bm = blockIdx.y * 64;
  const int bn = blockIdx.x * 128;
  const int wm = (wave >> 1) * 32;
  const int wn = (wave & 1) * 64;
  const int frow = lane & 15;
  const int fks  = (((lane >> 4) ^ ((frow >> 1) & 3)) * 8);  // swizzled chunk
  const int K = 1024;

  f32x4 acc[2][4] = {};

  const int row0 = tid >> 2, cc0 = tid & 3;
  const int scc = (cc0 ^ ((row0 >> 1) & 3)) * 8;   // pre-swizzled source chunk
  const unsigned short* Arow  = A  + (size_t)(bm + row0) * K + scc;
  const unsigned short* Brow0 = Bt + (size_t)(bn + row0) * K + scc;
  const unsigned short* Brow1 = Bt + (size_t)(bn + row0 + 64) * K + scc;

  // stage one 32-K sub-tile (3 GLDS)
#define STAGEP(bf, k1) do { \
    GLDS(Arow  + (k1), As[bf] + (size_t)tid * 8); \
    GLDS(Brow0 + (k1), Bs[bf] + (size_t)tid * 8); \
    GLDS(Brow1 + (k1), Bs[bf] + (size_t)(tid + 256) * 8); \
  } while (0)

  // prologue: both sub-tiles of span 0 into buffers 0,1
  STAGEP(0, 0);
  STAGEP(1, 32);

  const int NT = K / 64;            // 16 barrier spans
  for (int t = 0; t < NT; ++t) {
    const int p = t & 1;            // span t lives in bufs {2p, 2p+1}
    __syncthreads();                // span t ready

    if (t + 1 < NT) {               // stage span t+1 into the other pair
      STAGEP(2 * (1 - p),     (t + 1) * 64);
      STAGEP(2 * (1 - p) + 1, (t + 1) * 64 + 32);
    }

#pragma unroll
    for (int sub = 0; sub < 2; ++sub) {
      const unsigned short* Asb = As[2 * p + sub];
      const unsigned short* Bsb = Bs[2 * p + sub];
      bf16x8 af[2], bfr[4];
#pragma unroll
      for (int q = 0; q < 2; ++q)
        af[q] = *(const bf16x8*)(Asb + (wm + q * 16 + frow) * 32 + fks);
#pragma unroll
      for (int q = 0; q < 4; ++q)
        bfr[q] = *(const bf16x8*)(Bsb + (wn + q * 16 + frow) * 32 + fks);
#pragma unroll
      for (int mt = 0; mt < 2; ++mt)
#pragma unroll
        for (int nt = 0; nt < 4; ++nt)
          acc[mt][nt] = __builtin_amdgcn_mfma_f32_16x16x32_bf16(af[mt], bfr[nt], acc[mt][nt], 0, 0, 0);
    }
  }
#undef STAGEP

  const int er0  = (lane >> 4) * 4;
  const int ecol = lane & 15;
#pragma unroll
  for (int nt = 0; nt < 4; ++nt) {
    int col = bn + wn + nt * 16 + ecol;
    float bv = bias[col];
#pragma unroll
    for (int mt = 0; mt < 2; ++mt)
#pragma unroll
      for (int r = 0; r < 4; ++r) {
        int rowg = bm + wm + mt * 16 + er0 + r;
        Co[(size_t)rowg * CC + col] = acc[mt][nt][r] + bv;
      }
  }
}

// ---------------------------------------------------------------- launcher
extern "C" void kernel_launch(void* const* d_in, const int* in_sizes, int n_in,
                              void* d_out, int out_size, void* d_ws, size_t ws_size,
                              hipStream_t stream)
{
  const float* x      = (const float*)d_in[0];
  const float* w_qkv  = (const float*)d_in[1];
  const float* b_qkv  = (const float*)d_in[2];
  const float* w_proj = (const float*)d_in[3];
  const float* b_proj = (const float*)d_in[4];
  const float* fcos   = (const float*)d_in[5];
  const float* fsin   = (const float*)d_in[6];
  float* out = (float*)d_out;

  char* ws = (char*)d_ws;
  unsigned short* xb     = (unsigned short*)(ws);              //  8 MB
  unsigned short* wqkvb  = (unsigned short*)(ws + 8388608);    //  6 MB
  unsigned short* wprojb = (unsigned short*)(ws + 14680064);   //  2 MB
  unsigned short* Qb     = (unsigned short*)(ws + 16777216);   //  8 MB
  unsigned short* Kb     = (unsigned short*)(ws + 25165824);   //  8 MB
  unsigned short* Vtb    = (unsigned short*)(ws + 33554432);   //  8 MB
  unsigned short* aob    = (unsigned short*)(ws + 41943040);   //  8 MB

  k_cvt<<<8192, 256, 0, stream>>>(x, w_qkv, w_proj, xb, wqkvb, wprojb);

  k_gemm_qkv<<<dim3(24, 32), 256, 0, stream>>>(xb, wqkvb, b_qkv, fcos, fsin,
                                               Qb, Kb, Vtb);

  k_attn<<<256, 512, 0, stream>>>(Qb, Kb, Vtb, aob);

  k_gemm_proj<<<dim3(8, 64), 256, 0, stream>>>(aob, wprojb, b_proj, out);
}

// Round 15
// 190.684 us; speedup vs baseline: 1.0829x; 1.0303x over previous
//
#include <hip/hip_runtime.h>
#include <hip/hip_bf16.h>
#include <stdint.h>

#define BB 2
#define NN 2048
#define CC 1024
#define HH 16
#define DD 64
#define C3 3072

typedef __attribute__((ext_vector_type(8))) short bf16x8;
typedef __attribute__((ext_vector_type(4))) short bf16x4;
typedef __attribute__((ext_vector_type(4))) float f32x4;
typedef __attribute__((ext_vector_type(16))) float f32x16;
typedef __attribute__((ext_vector_type(4))) unsigned short ushort4_t;

__device__ __forceinline__ unsigned short f2bf(float f) {
  union { float f; unsigned u; } v; v.f = f;
  unsigned r = v.u + 0x7FFFu + ((v.u >> 16) & 1u);
  return (unsigned short)(r >> 16);
}

#if __has_builtin(__builtin_amdgcn_exp2f)
#define EXP2(x) __builtin_amdgcn_exp2f(x)
#else
#define EXP2(x) exp2f(x)
#endif

// truncating pack of two f32 -> one VGPR holding {lo16=hi(a), hi16=hi(b)}
__device__ __forceinline__ unsigned pack_bf2(float a, float b) {
  union { float f; unsigned u; } ua, ub; ua.f = a; ub.f = b;
#if __has_builtin(__builtin_amdgcn_perm)
  return __builtin_amdgcn_perm(ub.u, ua.u, 0x07060302u);
#else
  return (ua.u >> 16) | (ub.u & 0xFFFF0000u);
#endif
}

// 0.125 (1/sqrt(D)) * log2(e): folded into Q so softmax is raw v_exp_f32 (2^x)
#define QSCALE 0.18033688f

// async global->LDS, 16B per lane; LDS dest must be wave-uniform base + lane*16
#define GLDS(g, l) __builtin_amdgcn_global_load_lds( \
    (const __attribute__((address_space(1))) void*)(g), \
    (__attribute__((address_space(3))) void*)(l), 16, 0, 0)

// ----------------------------------------- merged fp32->bf16 converts (3 bufs)
__global__ __launch_bounds__(256) void k_cvt(
    const float* __restrict__ x, const float* __restrict__ wq,
    const float* __restrict__ wp,
    unsigned short* __restrict__ xb, unsigned short* __restrict__ wqb,
    unsigned short* __restrict__ wpb)
{
  int blk = blockIdx.x;
  const float* s; unsigned short* d; int i;
  if (blk < 4096)      { s = x;  d = xb;  i = blk * 256 + threadIdx.x; }
  else if (blk < 7168) { s = wq; d = wqb; i = (blk - 4096) * 256 + threadIdx.x; }
  else                 { s = wp; d = wpb; i = (blk - 7168) * 256 + threadIdx.x; }
  float4 v = ((const float4*)s)[i];
  ushort4_t o;
  o.x = f2bf(v.x); o.y = f2bf(v.y); o.z = f2bf(v.z); o.w = f2bf(v.w);
  ((ushort4_t*)d)[i] = o;
}

// -------------------------------- GEMM1 fused: qkv = x@Wqkv^T + b, RoPE, pack
// v17 form (best known): BK=32, 2 buffers, one __syncthreads/iter, T2
// both-sides bank swizzle (conflicts 3.3M -> 164K), 32KB LDS (3 blocks/CU --
// any more LDS is an occupancy cliff, v20). Epilogue: RoPE in registers,
// wave-private LDS tile, Region V staged transposed with PI-PERMUTED kv order.
__global__ __launch_bounds__(256) void k_gemm_qkv(
    const unsigned short* __restrict__ A, const unsigned short* __restrict__ Bt,
    const float* __restrict__ bias,
    const float* __restrict__ cosb, const float* __restrict__ sinb,
    unsigned short* __restrict__ Qg, unsigned short* __restrict__ Kg,
    unsigned short* __restrict__ Vt)
{
  __shared__ __align__(16) unsigned short Sh[16384];  // 32KB: 2x(As+Bs) / epilogue
  const int tid  = threadIdx.x;
  const int lane = tid & 63;
  const int wave = tid >> 6;
  const int bm = blockIdx.y * 128;
  const int bn = blockIdx.x * 128;
  const int wm = (wave >> 1) * 64;
  const int wn = (wave & 1) * 64;
  const int frow = lane & 15;
  const int fks  = (((lane >> 4) ^ ((frow >> 1) & 3)) * 8);  // swizzled chunk
  const int K = 1024;
  const int NIT = K / 32;

  f32x4 acc[4][4] = {};

  const int row0 = tid >> 2, cc0 = tid & 3;
  const int row1 = row0 + 64;
  const int scc = (cc0 ^ ((row0 >> 1) & 3)) * 8;   // pre-swizzled source chunk
  const unsigned short* Arow0 = A  + (size_t)(bm + row0) * K + scc;
  const unsigned short* Arow1 = A  + (size_t)(bm + row1) * K + scc;
  const unsigned short* Brow0 = Bt + (size_t)(bn + row0) * K + scc;
  const unsigned short* Brow1 = Bt + (size_t)(bn + row1) * K + scc;

  GLDS(Arow0, Sh + (size_t)tid * 8);
  GLDS(Brow0, Sh + 4096 + (size_t)tid * 8);
  GLDS(Arow1, Sh + (size_t)(tid + 256) * 8);
  GLDS(Brow1, Sh + 4096 + (size_t)(tid + 256) * 8);

  for (int it = 0; it < NIT; ++it) {
    const int p = it & 1;
    const unsigned short* As = Sh + p * 8192;
    const unsigned short* Bs = As + 4096;
    __syncthreads();

    if (it + 1 < NIT) {
      const int k1 = (it + 1) * 32;
      unsigned short* An = Sh + (1 - p) * 8192;
      GLDS(Arow0 + k1, An + (size_t)tid * 8);
      GLDS(Brow0 + k1, An + 4096 + (size_t)tid * 8);
      GLDS(Arow1 + k1, An + (size_t)(tid + 256) * 8);
      GLDS(Brow1 + k1, An + 4096 + (size_t)(tid + 256) * 8);
    }

    bf16x8 af[4], bfr[4];
#pragma unroll
    for (int t = 0; t < 4; ++t) {
      af[t]  = *(const bf16x8*)(As + (wm + t * 16 + frow) * 32 + fks);
      bfr[t] = *(const bf16x8*)(Bs + (wn + t * 16 + frow) * 32 + fks);
    }
#pragma unroll
    for (int mt = 0; mt < 4; ++mt)
#pragma unroll
      for (int nt = 0; nt < 4; ++nt)
        acc[mt][nt] = __builtin_amdgcn_mfma_f32_16x16x32_bf16(af[mt], bfr[nt], acc[mt][nt], 0, 0, 0);
  }
  __syncthreads();   // staging LDS now reusable for epilogue

  const int er0  = (lane >> 4) * 4;
  const int ecol = lane & 15;
  const int region = bn >> 10;                 // wave-uniform: 0=Q,1=K,2=V
  const int gcol0 = bn + wn;                   // 64-aligned -> one head
  const int h  = (gcol0 >> 6) & 15;
  const int rowg0 = bm + wm;                   // wave-uniform
  const int b  = rowg0 >> 11;
  const int n0 = rowg0 & (NN - 1);
  unsigned short* wt = Sh + wave * 4096;       // 64x64 wave-private tile

#pragma unroll
  for (int nt = 0; nt < 4; ++nt) {
    const int c64 = nt * 16 + ecol;            // d within head
    const float bv = bias[gcol0 + c64];
    const int ii  = c64 >> 1;
#pragma unroll
    for (int mt = 0; mt < 4; ++mt)
#pragma unroll
      for (int r = 0; r < 4; ++r) {
        const int ml = mt * 16 + er0 + r;      // row within wave tile
        const int n  = n0 + ml;
        float v = acc[mt][nt][r] + bv;
        float vp = __shfl_xor(v, 1, 64);       // pair partner (d^1)
        if (region == 2) {
          wt[c64 * 64 + ((((ml >> 3) ^ (c64 & 7)) << 3) | (ml & 7))] = f2bf(v);
        } else {
          float cth = cosb[n * 32 + ii], sth = sinb[n * 32 + ii];
          float ov = (c64 & 1) ? (vp * sth + v * cth)
                               : (v * cth - vp * sth);
          if (region == 0) ov *= QSCALE;
          wt[ml * 64 + ((((c64 >> 3) ^ (ml & 7)) << 3) | (c64 & 7))] = f2bf(ov);
        }
      }
  }

  const int rr = lane >> 3, cc = lane & 7;
  if (region == 2) {
    // pi-permuted store: stored[col] = V[kv = P(col)], P = swap bits 2,3.
    unsigned short* dst = Vt + (size_t)(b * HH + h) * DD * NN + n0;
    const int q8a = (cc >> 1) * 2;
    const int q8b = q8a + 1;
    const int half = (cc & 1) * 4;
#pragma unroll
    for (int it = 0; it < 8; ++it) {
      int dl = it * 8 + rr;
      union { bf16x4 h[2]; bf16x8 w; } vv;
      vv.h[0] = *(const bf16x4*)(wt + dl * 64 + ((q8a ^ (dl & 7)) << 3) + half);
      vv.h[1] = *(const bf16x4*)(wt + dl * 64 + ((q8b ^ (dl & 7)) << 3) + half);
      *(bf16x8*)(dst + (size_t)dl * NN + cc * 8) = vv.w;
    }
  } else {
    unsigned short* dqk = ((region == 0) ? Qg : Kg) +
                          ((size_t)(b * HH + h) * NN + n0) * DD;
#pragma unroll
    for (int it = 0; it < 8; ++it) {
      int ml = it * 8 + rr;
      bf16x8 vv = *(const bf16x8*)(wt + ml * 64 + ((cc ^ (ml & 7)) << 3));
      *(bf16x8*)(dqk + (size_t)ml * DD + cc * 8) = vv;
    }
  }
}

// ----------------------------------------------------- flash attention v19
// (best known). 256 q/block, 512 thr/8 waves, grid 256 with XCD swizzle;
// KVBLK=128 as two 64-kv sub-tiles/span, 4+4 bufs (64KB), __syncthreads
// dbuf (counted-vmcnt depth-2 REGRESSED -4.4us, v21; 2-wave blocks -5.7,
// v13 -- this double-buffer barrier schedule is the measured optimum).
__global__ __launch_bounds__(512) void k_attn(
    const unsigned short* __restrict__ Qg, const unsigned short* __restrict__ Kg,
    const unsigned short* __restrict__ Vtg, unsigned short* __restrict__ Og)
{
  __shared__ __align__(16) unsigned short Ks[4][64 * 64];
  __shared__ __align__(16) unsigned short Vs[4][64 * 64];

  const int tid  = threadIdx.x;
  const int lane = tid & 63;
  const int wave = tid >> 6;                    // 0..7
  const int wid  = (blockIdx.x & 7) * 32 + (blockIdx.x >> 3);  // XCD-clustered
  const int bh = wid >> 3;                      // 0..31
  const int qt = wid & 7;                       // 0..7
  const int q0 = qt * 256 + wave * 32;
  const int l31 = lane & 31;
  const int hi  = lane >> 5;
  const int s7  = l31 & 7;

  const unsigned short* Qb = Qg  + (size_t)bh * NN * DD;
  const unsigned short* Kb = Kg  + (size_t)bh * NN * DD;
  const unsigned short* Vb = Vtg + (size_t)bh * DD * NN;

  // one byte-offset table for ALL LDS reads: row l31, 16B slot (2i+hi)^s7
  int soffB[4];
#pragma unroll
  for (int i = 0; i < 4; ++i)
    soffB[i] = (l31 * 64 + (((2 * i + hi) ^ s7) << 3)) * 2;

  // Q fragments (B-operand of 32x32x16: n = l31 = q, k = hi*8+j = d)
  bf16x8 qf[4];
#pragma unroll
  for (int dc = 0; dc < 4; ++dc)
    qf[dc] = *(const bf16x8*)(Qb + (size_t)(q0 + l31) * DD + dc * 16 + hi * 8);

  bf16x8 ones;
#pragma unroll
  for (int i = 0; i < 8; ++i) ones[i] = (short)0x3F80;
  const f32x16 zero16 = {};   // loop-invariant C for first MFMA of each chain

  f32x16 oacc[2] = {};
  f32x16 lacc = {};

  const int row0 = tid >> 3, cc0 = tid & 7;     // row0 0..63 (512 threads)
  const int sw0 = (cc0 ^ (row0 & 7)) * 8;

  // stage one 64x64 K sub-tile + one 64x64 V sub-tile (2 GLDS, 512 lanes)
#define STAGE64(bf, j) do { \
    GLDS(Kb + (size_t)((j) + row0) * DD + sw0, Ks[bf] + (size_t)tid * 8); \
    GLDS(Vb + (size_t)row0 * NN + (j) + sw0,   Vs[bf] + (size_t)tid * 8); \
  } while (0)

  // prologue: both sub-tiles of kv-tile 0 into buffers 0,1
  STAGE64(0, 0);
  STAGE64(1, 64);

  const int NT = NN / 128;          // 16 barrier spans
#pragma unroll 2
  for (int t = 0; t < NT; ++t) {
    const int p = t & 1;            // tile t lives in bufs {2p, 2p+1}
    __syncthreads();                // drains vmcnt+lgkmcnt: tile t ready

    if (t + 1 < NT) {               // stage tile t+1 into bufs {2(1-p), ...+1}
      STAGE64(2 * (1 - p),     (t + 1) * 128);
      STAGE64(2 * (1 - p) + 1, (t + 1) * 128 + 64);
    }

#pragma unroll
    for (int sub = 0; sub < 2; ++sub) {
      const char* KsB = (const char*)Ks[2 * p + sub];
      const char* VsB = (const char*)Vs[2 * p + sub];

      // S^T = K Q^T : A = K (m=kv), B = Q (n=q); 2 kv-halves x 4 d-chunks
      f32x16 sacc[2];
      __builtin_amdgcn_s_setprio(1);
#pragma unroll
      for (int T = 0; T < 2; ++T) {
        bf16x8 kf0 = *(const bf16x8*)(KsB + T * 4096 + soffB[0]);
        sacc[T] = __builtin_amdgcn_mfma_f32_32x32x16_bf16(kf0, qf[0], zero16, 0, 0, 0);
#pragma unroll
        for (int dc = 1; dc < 4; ++dc) {
          bf16x8 kf = *(const bf16x8*)(KsB + T * 4096 + soffB[dc]);
          sacc[T] = __builtin_amdgcn_mfma_f32_32x32x16_bf16(kf, qf[dc], sacc[T], 0, 0, 0);
        }
      }
      __builtin_amdgcn_s_setprio(0);

      // per kv-half: exp -> pack (pi-order, no swaps) -> PV + l MFMAs
#pragma unroll
      for (int T = 0; T < 2; ++T) {
        unsigned pk[8];
#pragma unroll
        for (int jj = 0; jj < 8; ++jj) {
          float e0 = EXP2(sacc[T][2 * jj]);
          float e1 = EXP2(sacc[T][2 * jj + 1]);
          pk[jj] = pack_bf2(e0, e1);
        }
        union { unsigned u[4]; bf16x8 v; } fa, fb;
        fa.u[0] = pk[0]; fa.u[1] = pk[1]; fa.u[2] = pk[2]; fa.u[3] = pk[3];
        fb.u[0] = pk[4]; fb.u[1] = pk[5]; fb.u[2] = pk[6]; fb.u[3] = pk[7];
        // fa covers kv T*32 + g(hi,j); fb covers kv T*32 + 16 + g(hi,j)
        // Vs pi-order: frag (T,c') = b128 at slot 4T+2c'+hi -> soffB[2T+c']
        __builtin_amdgcn_s_setprio(1);
#pragma unroll
        for (int dt = 0; dt < 2; ++dt) {
          bf16x8 v0 = *(const bf16x8*)(VsB + dt * 4096 + soffB[2 * T + 0]);
          bf16x8 v1 = *(const bf16x8*)(VsB + dt * 4096 + soffB[2 * T + 1]);
          oacc[dt] = __builtin_amdgcn_mfma_f32_32x32x16_bf16(fa.v, v0, oacc[dt], 0, 0, 0);
          oacc[dt] = __builtin_amdgcn_mfma_f32_32x32x16_bf16(fb.v, v1, oacc[dt], 0, 0, 0);
        }
        lacc = __builtin_amdgcn_mfma_f32_32x32x16_bf16(fa.v, ones, lacc, 0, 0, 0);
        lacc = __builtin_amdgcn_mfma_f32_32x32x16_bf16(fb.v, ones, lacc, 0, 0, 0);
        __builtin_amdgcn_s_setprio(0);
      }
    }
  }
#undef STAGE64

  // epilogue: lacc[r] = l[q=crow(r,hi)] (uniform in n). O row q, col d = l31.
  const int b = bh >> 4;
  const int h = bh & 15;
#pragma unroll
  for (int r = 0; r < 16; ++r) {
    const int qr = (r & 3) + 8 * (r >> 2) + 4 * hi;
    const float linv = 1.0f / lacc[r];
    unsigned short* orow = Og + (size_t)(b * NN + q0 + qr) * CC + h * DD + l31;
    orow[0]  = f2bf(oacc[0][r] * linv);
    orow[32] = f2bf(oacc[1][r] * linv);
  }
}

// ------------------------------- GEMM2: out = aob @ Wproj^T + b (fp32 out)
// v18 (best known): span-doubled BK=64 (two independent 32-K sub-tiles, 4
// staging buffers, 48KB LDS; grid 512 = 2 blocks/CU is the limit either
// way), T2 both-sides swizzle.
__global__ __launch_bounds__(256) void k_gemm_proj(
    const unsigned short* __restrict__ A, const unsigned short* __restrict__ Bt,
    const float* __restrict__ bias, float* __restrict__ Co)
{
  __shared__ __align__(16) unsigned short As[4][64 * 32];
  __shared__ __align__(16) unsigned short Bs[4][128 * 32];
  const int tid  = threadIdx.x;
  const int lane = tid & 63;
  const int wave = tid >> 6;
  const int bm = blockIdx.y * 64;
  const int bn = blockIdx.x * 128;
  const int wm = (wave >> 1) * 32;
  const int wn = (wave & 1) * 64;
  const int frow = lane & 15;
  const int fks  = (((lane >> 4) ^ ((frow >> 1) & 3)) * 8);  // swizzled chunk
  const int K = 1024;

  f32x4 acc[2][4] = {};

  const int row0 = tid >> 2, cc0 = tid & 3;
  const int scc = (cc0 ^ ((row0 >> 1) & 3)) * 8;   // pre-swizzled source chunk
  const unsigned short* Arow  = A  + (size_t)(bm + row0) * K + scc;
  const unsigned short* Brow0 = Bt + (size_t)(bn + row0) * K + scc;
  const unsigned short* Brow1 = Bt + (size_t)(bn + row0 + 64) * K + scc;

  // stage one 32-K sub-tile (3 GLDS)
#define STAGEP(bf, k1) do { \
    GLDS(Arow  + (k1), As[bf] + (size_t)tid * 8); \
    GLDS(Brow0 + (k1), Bs[bf] + (size_t)tid * 8); \
    GLDS(Brow1 + (k1), Bs[bf] + (size_t)(tid + 256) * 8); \
  } while (0)

  // prologue: both sub-tiles of span 0 into buffers 0,1
  STAGEP(0, 0);
  STAGEP(1, 32);

  const int NT = K / 64;            // 16 barrier spans
  for (int t = 0; t < NT; ++t) {
    const int p = t & 1;            // span t lives in bufs {2p, 2p+1}
    __syncthreads();                // span t ready

    if (t + 1 < NT) {               // stage span t+1 into the other pair
      STAGEP(2 * (1 - p),     (t + 1) * 64);
      STAGEP(2 * (1 - p) + 1, (t + 1) * 64 + 32);
    }

#pragma unroll
    for (int sub = 0; sub < 2; ++sub) {
      const unsigned short* Asb = As[2 * p + sub];
      const unsigned short* Bsb = Bs[2 * p + sub];
      bf16x8 af[2], bfr[4];
#pragma unroll
      for (int q = 0; q < 2; ++q)
        af[q] = *(const bf16x8*)(Asb + (wm + q * 16 + frow) * 32 + fks);
#pragma unroll
      for (int q = 0; q < 4; ++q)
        bfr[q] = *(const bf16x8*)(Bsb + (wn + q * 16 + frow) * 32 + fks);
#pragma unroll
      for (int mt = 0; mt < 2; ++mt)
#pragma unroll
        for (int nt = 0; nt < 4; ++nt)
          acc[mt][nt] = __builtin_amdgcn_mfma_f32_16x16x32_bf16(af[mt], bfr[nt], acc[mt][nt], 0, 0, 0);
    }
  }
#undef STAGEP

  const int er0  = (lane >> 4) * 4;
  const int ecol = lane & 15;
#pragma unroll
  for (int nt = 0; nt < 4; ++nt) {
    int col = bn + wn + nt * 16 + ecol;
    float bv = bias[col];
#pragma unroll
    for (int mt = 0; mt < 2; ++mt)
#pragma unroll
      for (int r = 0; r < 4; ++r) {
        int rowg = bm + wm + mt * 16 + er0 + r;
        Co[(size_t)rowg * CC + col] = acc[mt][nt][r] + bv;
      }
  }
}

// ---------------------------------------------------------------- launcher
extern "C" void kernel_launch(void* const* d_in, const int* in_sizes, int n_in,
                              void* d_out, int out_size, void* d_ws, size_t ws_size,
                              hipStream_t stream)
{
  const float* x      = (const float*)d_in[0];
  const float* w_qkv  = (const float*)d_in[1];
  const float* b_qkv  = (const float*)d_in[2];
  const float* w_proj = (const float*)d_in[3];
  const float* b_proj = (const float*)d_in[4];
  const float* fcos   = (const float*)d_in[5];
  const float* fsin   = (const float*)d_in[6];
  float* out = (float*)d_out;

  char* ws = (char*)d_ws;
  unsigned short* xb     = (unsigned short*)(ws);              //  8 MB
  unsigned short* wqkvb  = (unsigned short*)(ws + 8388608);    //  6 MB
  unsigned short* wprojb = (unsigned short*)(ws + 14680064);   //  2 MB
  unsigned short* Qb     = (unsigned short*)(ws + 16777216);   //  8 MB
  unsigned short* Kb     = (unsigned short*)(ws + 25165824);   //  8 MB
  unsigned short* Vtb    = (unsigned short*)(ws + 33554432);   //  8 MB
  unsigned short* aob    = (unsigned short*)(ws + 41943040);   //  8 MB

  k_cvt<<<8192, 256, 0, stream>>>(x, w_qkv, w_proj, xb, wqkvb, wprojb);

  k_gemm_qkv<<<dim3(24, 32), 256, 0, stream>>>(xb, wqkvb, b_qkv, fcos, fsin,
                                               Qb, Kb, Vtb);

  k_attn<<<256, 512, 0, stream>>>(Qb, Kb, Vtb, aob);

  k_gemm_proj<<<dim3(8, 64), 256, 0, stream>>>(aob, wprojb, b_proj, out);
}

// Round 16
// 190.572 us; speedup vs baseline: 1.0835x; 1.0006x over previous
//
#include <hip/hip_runtime.h>
#include <hip/hip_bf16.h>
#include <stdint.h>

#define BB 2
#define NN 2048
#define CC 1024
#define HH 16
#define DD 64
#define C3 3072

typedef __attribute__((ext_vector_type(8))) short bf16x8;
typedef __attribute__((ext_vector_type(4))) short bf16x4;
typedef __attribute__((ext_vector_type(4))) float f32x4;
typedef __attribute__((ext_vector_type(16))) float f32x16;
typedef __attribute__((ext_vector_type(4))) unsigned short ushort4_t;

__device__ __forceinline__ unsigned short f2bf(float f) {
  union { float f; unsigned u; } v; v.f = f;
  unsigned r = v.u + 0x7FFFu + ((v.u >> 16) & 1u);
  return (unsigned short)(r >> 16);
}

#if __has_builtin(__builtin_amdgcn_exp2f)
#define EXP2(x) __builtin_amdgcn_exp2f(x)
#else
#define EXP2(x) exp2f(x)
#endif

// truncating pack of two f32 -> one VGPR holding {lo16=hi(a), hi16=hi(b)}
__device__ __forceinline__ unsigned pack_bf2(float a, float b) {
  union { float f; unsigned u; } ua, ub; ua.f = a; ub.f = b;
#if __has_builtin(__builtin_amdgcn_perm)
  return __builtin_amdgcn_perm(ub.u, ua.u, 0x07060302u);
#else
  return (ua.u >> 16) | (ub.u & 0xFFFF0000u);
#endif
}

// 0.125 (1/sqrt(D)) * log2(e): folded into Q so softmax is raw v_exp_f32 (2^x)
#define QSCALE 0.18033688f

// async global->LDS, 16B per lane; LDS dest must be wave-uniform base + lane*16
#define GLDS(g, l) __builtin_amdgcn_global_load_lds( \
    (const __attribute__((address_space(1))) void*)(g), \
    (__attribute__((address_space(3))) void*)(l), 16, 0, 0)

// ----------------------------------------- merged fp32->bf16 converts (3 bufs)
__global__ __launch_bounds__(256) void k_cvt(
    const float* __restrict__ x, const float* __restrict__ wq,
    const float* __restrict__ wp,
    unsigned short* __restrict__ xb, unsigned short* __restrict__ wqb,
    unsigned short* __restrict__ wpb)
{
  int blk = blockIdx.x;
  const float* s; unsigned short* d; int i;
  if (blk < 4096)      { s = x;  d = xb;  i = blk * 256 + threadIdx.x; }
  else if (blk < 7168) { s = wq; d = wqb; i = (blk - 4096) * 256 + threadIdx.x; }
  else                 { s = wp; d = wpb; i = (blk - 7168) * 256 + threadIdx.x; }
  float4 v = ((const float4*)s)[i];
  ushort4_t o;
  o.x = f2bf(v.x); o.y = f2bf(v.y); o.z = f2bf(v.z); o.w = f2bf(v.w);
  ((ushort4_t*)d)[i] = o;
}

// -------------------------------- GEMM1 fused: qkv = x@Wqkv^T + b, RoPE, pack
// v17 form (best known): BK=32, 2 buffers, one __syncthreads/iter, T2
// both-sides bank swizzle (conflicts 3.3M -> 164K), 32KB LDS (3 blocks/CU --
// any more LDS is an occupancy cliff, v20). Epilogue: RoPE in registers,
// wave-private LDS tile, Region V staged transposed with PI-PERMUTED kv order.
__global__ __launch_bounds__(256) void k_gemm_qkv(
    const unsigned short* __restrict__ A, const unsigned short* __restrict__ Bt,
    const float* __restrict__ bias,
    const float* __restrict__ cosb, const float* __restrict__ sinb,
    unsigned short* __restrict__ Qg, unsigned short* __restrict__ Kg,
    unsigned short* __restrict__ Vt)
{
  __shared__ __align__(16) unsigned short Sh[16384];  // 32KB: 2x(As+Bs) / epilogue
  const int tid  = threadIdx.x;
  const int lane = tid & 63;
  const int wave = tid >> 6;
  const int bm = blockIdx.y * 128;
  const int bn = blockIdx.x * 128;
  const int wm = (wave >> 1) * 64;
  const int wn = (wave & 1) * 64;
  const int frow = lane & 15;
  const int fks  = (((lane >> 4) ^ ((frow >> 1) & 3)) * 8);  // swizzled chunk
  const int K = 1024;
  const int NIT = K / 32;

  f32x4 acc[4][4] = {};

  const int row0 = tid >> 2, cc0 = tid & 3;
  const int row1 = row0 + 64;
  const int scc = (cc0 ^ ((row0 >> 1) & 3)) * 8;   // pre-swizzled source chunk
  const unsigned short* Arow0 = A  + (size_t)(bm + row0) * K + scc;
  const unsigned short* Arow1 = A  + (size_t)(bm + row1) * K + scc;
  const unsigned short* Brow0 = Bt + (size_t)(bn + row0) * K + scc;
  const unsigned short* Brow1 = Bt + (size_t)(bn + row1) * K + scc;

  GLDS(Arow0, Sh + (size_t)tid * 8);
  GLDS(Brow0, Sh + 4096 + (size_t)tid * 8);
  GLDS(Arow1, Sh + (size_t)(tid + 256) * 8);
  GLDS(Brow1, Sh + 4096 + (size_t)(tid + 256) * 8);

  for (int it = 0; it < NIT; ++it) {
    const int p = it & 1;
    const unsigned short* As = Sh + p * 8192;
    const unsigned short* Bs = As + 4096;
    __syncthreads();

    if (it + 1 < NIT) {
      const int k1 = (it + 1) * 32;
      unsigned short* An = Sh + (1 - p) * 8192;
      GLDS(Arow0 + k1, An + (size_t)tid * 8);
      GLDS(Brow0 + k1, An + 4096 + (size_t)tid * 8);
      GLDS(Arow1 + k1, An + (size_t)(tid + 256) * 8);
      GLDS(Brow1 + k1, An + 4096 + (size_t)(tid + 256) * 8);
    }

    bf16x8 af[4], bfr[4];
#pragma unroll
    for (int t = 0; t < 4; ++t) {
      af[t]  = *(const bf16x8*)(As + (wm + t * 16 + frow) * 32 + fks);
      bfr[t] = *(const bf16x8*)(Bs + (wn + t * 16 + frow) * 32 + fks);
    }
#pragma unroll
    for (int mt = 0; mt < 4; ++mt)
#pragma unroll
      for (int nt = 0; nt < 4; ++nt)
        acc[mt][nt] = __builtin_amdgcn_mfma_f32_16x16x32_bf16(af[mt], bfr[nt], acc[mt][nt], 0, 0, 0);
  }
  __syncthreads();   // staging LDS now reusable for epilogue

  const int er0  = (lane >> 4) * 4;
  const int ecol = lane & 15;
  const int region = bn >> 10;                 // wave-uniform: 0=Q,1=K,2=V
  const int gcol0 = bn + wn;                   // 64-aligned -> one head
  const int h  = (gcol0 >> 6) & 15;
  const int rowg0 = bm + wm;                   // wave-uniform
  const int b  = rowg0 >> 11;
  const int n0 = rowg0 & (NN - 1);
  unsigned short* wt = Sh + wave * 4096;       // 64x64 wave-private tile

#pragma unroll
  for (int nt = 0; nt < 4; ++nt) {
    const int c64 = nt * 16 + ecol;            // d within head
    const float bv = bias[gcol0 + c64];
    const int ii  = c64 >> 1;
#pragma unroll
    for (int mt = 0; mt < 4; ++mt)
#pragma unroll
      for (int r = 0; r < 4; ++r) {
        const int ml = mt * 16 + er0 + r;      // row within wave tile
        const int n  = n0 + ml;
        float v = acc[mt][nt][r] + bv;
        float vp = __shfl_xor(v, 1, 64);       // pair partner (d^1)
        if (region == 2) {
          wt[c64 * 64 + ((((ml >> 3) ^ (c64 & 7)) << 3) | (ml & 7))] = f2bf(v);
        } else {
          float cth = cosb[n * 32 + ii], sth = sinb[n * 32 + ii];
          float ov = (c64 & 1) ? (vp * sth + v * cth)
                               : (v * cth - vp * sth);
          if (region == 0) ov *= QSCALE;
          wt[ml * 64 + ((((c64 >> 3) ^ (ml & 7)) << 3) | (c64 & 7))] = f2bf(ov);
        }
      }
  }

  const int rr = lane >> 3, cc = lane & 7;
  if (region == 2) {
    // pi-permuted store: stored[col] = V[kv = P(col)], P = swap bits 2,3.
    unsigned short* dst = Vt + (size_t)(b * HH + h) * DD * NN + n0;
    const int q8a = (cc >> 1) * 2;
    const int q8b = q8a + 1;
    const int half = (cc & 1) * 4;
#pragma unroll
    for (int it = 0; it < 8; ++it) {
      int dl = it * 8 + rr;
      union { bf16x4 h[2]; bf16x8 w; } vv;
      vv.h[0] = *(const bf16x4*)(wt + dl * 64 + ((q8a ^ (dl & 7)) << 3) + half);
      vv.h[1] = *(const bf16x4*)(wt + dl * 64 + ((q8b ^ (dl & 7)) << 3) + half);
      *(bf16x8*)(dst + (size_t)dl * NN + cc * 8) = vv.w;
    }
  } else {
    unsigned short* dqk = ((region == 0) ? Qg : Kg) +
                          ((size_t)(b * HH + h) * NN + n0) * DD;
#pragma unroll
    for (int it = 0; it < 8; ++it) {
      int ml = it * 8 + rr;
      bf16x8 vv = *(const bf16x8*)(wt + ml * 64 + ((cc ^ (ml & 7)) << 3));
      *(bf16x8*)(dqk + (size_t)ml * DD + cc * 8) = vv;
    }
  }
}

// ----------------------------------------------------- flash attention v19
// (best known). 256 q/block, 512 thr/8 waves, grid 256 with XCD swizzle;
// KVBLK=128 as two 64-kv sub-tiles/span, 4+4 bufs (64KB), __syncthreads
// dbuf (counted-vmcnt depth-2 REGRESSED -4.4us, v21; 2-wave blocks -5.7,
// v13 -- this double-buffer barrier schedule is the measured optimum).
__global__ __launch_bounds__(512) void k_attn(
    const unsigned short* __restrict__ Qg, const unsigned short* __restrict__ Kg,
    const unsigned short* __restrict__ Vtg, unsigned short* __restrict__ Og)
{
  __shared__ __align__(16) unsigned short Ks[4][64 * 64];
  __shared__ __align__(16) unsigned short Vs[4][64 * 64];

  const int tid  = threadIdx.x;
  const int lane = tid & 63;
  const int wave = tid >> 6;                    // 0..7
  const int wid  = (blockIdx.x & 7) * 32 + (blockIdx.x >> 3);  // XCD-clustered
  const int bh = wid >> 3;                      // 0..31
  const int qt = wid & 7;                       // 0..7
  const int q0 = qt * 256 + wave * 32;
  const int l31 = lane & 31;
  const int hi  = lane >> 5;
  const int s7  = l31 & 7;

  const unsigned short* Qb = Qg  + (size_t)bh * NN * DD;
  const unsigned short* Kb = Kg  + (size_t)bh * NN * DD;
  const unsigned short* Vb = Vtg + (size_t)bh * DD * NN;

  // one byte-offset table for ALL LDS reads: row l31, 16B slot (2i+hi)^s7
  int soffB[4];
#pragma unroll
  for (int i = 0; i < 4; ++i)
    soffB[i] = (l31 * 64 + (((2 * i + hi) ^ s7) << 3)) * 2;

  // Q fragments (B-operand of 32x32x16: n = l31 = q, k = hi*8+j = d)
  bf16x8 qf[4];
#pragma unroll
  for (int dc = 0; dc < 4; ++dc)
    qf[dc] = *(const bf16x8*)(Qb + (size_t)(q0 + l31) * DD + dc * 16 + hi * 8);

  bf16x8 ones;
#pragma unroll
  for (int i = 0; i < 8; ++i) ones[i] = (short)0x3F80;
  const f32x16 zero16 = {};   // loop-invariant C for first MFMA of each chain

  f32x16 oacc[2] = {};
  f32x16 lacc = {};

  const int row0 = tid >> 3, cc0 = tid & 7;     // row0 0..63 (512 threads)
  const int sw0 = (cc0 ^ (row0 & 7)) * 8;

  // stage one 64x64 K sub-tile + one 64x64 V sub-tile (2 GLDS, 512 lanes)
#define STAGE64(bf, j) do { \
    GLDS(Kb + (size_t)((j) + row0) * DD + sw0, Ks[bf] + (size_t)tid * 8); \
    GLDS(Vb + (size_t)row0 * NN + (j) + sw0,   Vs[bf] + (size_t)tid * 8); \
  } while (0)

  // prologue: both sub-tiles of kv-tile 0 into buffers 0,1
  STAGE64(0, 0);
  STAGE64(1, 64);

  const int NT = NN / 128;          // 16 barrier spans
#pragma unroll 2
  for (int t = 0; t < NT; ++t) {
    const int p = t & 1;            // tile t lives in bufs {2p, 2p+1}
    __syncthreads();                // drains vmcnt+lgkmcnt: tile t ready

    if (t + 1 < NT) {               // stage tile t+1 into bufs {2(1-p), ...+1}
      STAGE64(2 * (1 - p),     (t + 1) * 128);
      STAGE64(2 * (1 - p) + 1, (t + 1) * 128 + 64);
    }

#pragma unroll
    for (int sub = 0; sub < 2; ++sub) {
      const char* KsB = (const char*)Ks[2 * p + sub];
      const char* VsB = (const char*)Vs[2 * p + sub];

      // S^T = K Q^T : A = K (m=kv), B = Q (n=q); 2 kv-halves x 4 d-chunks
      f32x16 sacc[2];
      __builtin_amdgcn_s_setprio(1);
#pragma unroll
      for (int T = 0; T < 2; ++T) {
        bf16x8 kf0 = *(const bf16x8*)(KsB + T * 4096 + soffB[0]);
        sacc[T] = __builtin_amdgcn_mfma_f32_32x32x16_bf16(kf0, qf[0], zero16, 0, 0, 0);
#pragma unroll
        for (int dc = 1; dc < 4; ++dc) {
          bf16x8 kf = *(const bf16x8*)(KsB + T * 4096 + soffB[dc]);
          sacc[T] = __builtin_amdgcn_mfma_f32_32x32x16_bf16(kf, qf[dc], sacc[T], 0, 0, 0);
        }
      }
      __builtin_amdgcn_s_setprio(0);

      // per kv-half: exp -> pack (pi-order, no swaps) -> PV + l MFMAs
#pragma unroll
      for (int T = 0; T < 2; ++T) {
        unsigned pk[8];
#pragma unroll
        for (int jj = 0; jj < 8; ++jj) {
          float e0 = EXP2(sacc[T][2 * jj]);
          float e1 = EXP2(sacc[T][2 * jj + 1]);
          pk[jj] = pack_bf2(e0, e1);
        }
        union { unsigned u[4]; bf16x8 v; } fa, fb;
        fa.u[0] = pk[0]; fa.u[1] = pk[1]; fa.u[2] = pk[2]; fa.u[3] = pk[3];
        fb.u[0] = pk[4]; fb.u[1] = pk[5]; fb.u[2] = pk[6]; fb.u[3] = pk[7];
        // fa covers kv T*32 + g(hi,j); fb covers kv T*32 + 16 + g(hi,j)
        // Vs pi-order: frag (T,c') = b128 at slot 4T+2c'+hi -> soffB[2T+c']
        __builtin_amdgcn_s_setprio(1);
#pragma unroll
        for (int dt = 0; dt < 2; ++dt) {
          bf16x8 v0 = *(const bf16x8*)(VsB + dt * 4096 + soffB[2 * T + 0]);
          bf16x8 v1 = *(const bf16x8*)(VsB + dt * 4096 + soffB[2 * T + 1]);
          oacc[dt] = __builtin_amdgcn_mfma_f32_32x32x16_bf16(fa.v, v0, oacc[dt], 0, 0, 0);
          oacc[dt] = __builtin_amdgcn_mfma_f32_32x32x16_bf16(fb.v, v1, oacc[dt], 0, 0, 0);
        }
        lacc = __builtin_amdgcn_mfma_f32_32x32x16_bf16(fa.v, ones, lacc, 0, 0, 0);
        lacc = __builtin_amdgcn_mfma_f32_32x32x16_bf16(fb.v, ones, lacc, 0, 0, 0);
        __builtin_amdgcn_s_setprio(0);
      }
    }
  }
#undef STAGE64

  // epilogue: lacc[r] = l[q=crow(r,hi)] (uniform in n). O row q, col d = l31.
  const int b = bh >> 4;
  const int h = bh & 15;
#pragma unroll
  for (int r = 0; r < 16; ++r) {
    const int qr = (r & 3) + 8 * (r >> 2) + 4 * hi;
    const float linv = 1.0f / lacc[r];
    unsigned short* orow = Og + (size_t)(b * NN + q0 + qr) * CC + h * DD + l31;
    orow[0]  = f2bf(oacc[0][r] * linv);
    orow[32] = f2bf(oacc[1][r] * linv);
  }
}

// ------------------------------- GEMM2: out = aob @ Wproj^T + b (fp32 out)
// v23: 4-BLOCKS/CU REGRID. 64x64 tiles, grid (16,64) = 1024 = exactly 4/CU;
// LDS = 4 bufs x (A 4KB + B 4KB) = 32KB (the occupancy sweet spot: v20
// showed >32KB rounds to 2 blocks/CU). 16 waves/CU = 4/SIMD, double v18's
// TLP -- co-resident blocks hide each other's barrier drains (the qkv-proven
// mechanism; v12/v21 showed 1-2-block regimes can't hide them). Same v18
// span structure (BK=64 as two 32-K sub-tiles, 16 barriers) and T2
// both-sides swizzle. Wave tile 32x32 (acc[2][2]); STAGEP = 2 GLDS.
__global__ __launch_bounds__(256) void k_gemm_proj(
    const unsigned short* __restrict__ A, const unsigned short* __restrict__ Bt,
    const float* __restrict__ bias, float* __restrict__ Co)
{
  __shared__ __align__(16) unsigned short As[4][64 * 32];
  __shared__ __align__(16) unsigned short Bs[4][64 * 32];
  const int tid  = threadIdx.x;
  const int lane = tid & 63;
  const int wave = tid >> 6;
  const int bm = blockIdx.y * 64;
  const int bn = blockIdx.x * 64;
  const int wm = (wave >> 1) * 32;
  const int wn = (wave & 1) * 32;
  const int frow = lane & 15;
  const int fks  = (((lane >> 4) ^ ((frow >> 1) & 3)) * 8);  // swizzled chunk
  const int K = 1024;

  f32x4 acc[2][2] = {};

  const int row0 = tid >> 2, cc0 = tid & 3;        // row0 0..63
  const int scc = (cc0 ^ ((row0 >> 1) & 3)) * 8;   // pre-swizzled source chunk
  const unsigned short* Arow = A  + (size_t)(bm + row0) * K + scc;
  const unsigned short* Brow = Bt + (size_t)(bn + row0) * K + scc;

  // stage one 32-K sub-tile (2 GLDS: A 64x32, B 64x32)
#define STAGEP(bf, k1) do { \
    GLDS(Arow + (k1), As[bf] + (size_t)tid * 8); \
    GLDS(Brow + (k1), Bs[bf] + (size_t)tid * 8); \
  } while (0)

  // prologue: both sub-tiles of span 0 into buffers 0,1
  STAGEP(0, 0);
  STAGEP(1, 32);

  const int NT = K / 64;            // 16 barrier spans
  for (int t = 0; t < NT; ++t) {
    const int p = t & 1;            // span t lives in bufs {2p, 2p+1}
    __syncthreads();                // span t ready

    if (t + 1 < NT) {               // stage span t+1 into the other pair
      STAGEP(2 * (1 - p),     (t + 1) * 64);
      STAGEP(2 * (1 - p) + 1, (t + 1) * 64 + 32);
    }

#pragma unroll
    for (int sub = 0; sub < 2; ++sub) {
      const unsigned short* Asb = As[2 * p + sub];
      const unsigned short* Bsb = Bs[2 * p + sub];
      bf16x8 af[2], bfr[2];
#pragma unroll
      for (int q = 0; q < 2; ++q) {
        af[q]  = *(const bf16x8*)(Asb + (wm + q * 16 + frow) * 32 + fks);
        bfr[q] = *(const bf16x8*)(Bsb + (wn + q * 16 + frow) * 32 + fks);
      }
#pragma unroll
      for (int mt = 0; mt < 2; ++mt)
#pragma unroll
        for (int nt = 0; nt < 2; ++nt)
          acc[mt][nt] = __builtin_amdgcn_mfma_f32_16x16x32_bf16(af[mt], bfr[nt], acc[mt][nt], 0, 0, 0);
    }
  }
#undef STAGEP

  const int er0  = (lane >> 4) * 4;
  const int ecol = lane & 15;
#pragma unroll
  for (int nt = 0; nt < 2; ++nt) {
    int col = bn + wn + nt * 16 + ecol;
    float bv = bias[col];
#pragma unroll
    for (int mt = 0; mt < 2; ++mt)
#pragma unroll
      for (int r = 0; r < 4; ++r) {
        int rowg = bm + wm + mt * 16 + er0 + r;
        Co[(size_t)rowg * CC + col] = acc[mt][nt][r] + bv;
      }
  }
}

// ---------------------------------------------------------------- launcher
extern "C" void kernel_launch(void* const* d_in, const int* in_sizes, int n_in,
                              void* d_out, int out_size, void* d_ws, size_t ws_size,
                              hipStream_t stream)
{
  const float* x      = (const float*)d_in[0];
  const float* w_qkv  = (const float*)d_in[1];
  const float* b_qkv  = (const float*)d_in[2];
  const float* w_proj = (const float*)d_in[3];
  const float* b_proj = (const float*)d_in[4];
  const float* fcos   = (const float*)d_in[5];
  const float* fsin   = (const float*)d_in[6];
  float* out = (float*)d_out;

  char* ws = (char*)d_ws;
  unsigned short* xb     = (unsigned short*)(ws);              //  8 MB
  unsigned short* wqkvb  = (unsigned short*)(ws + 8388608);    //  6 MB
  unsigned short* wprojb = (unsigned short*)(ws + 14680064);   //  2 MB
  unsigned short* Qb     = (unsigned short*)(ws + 16777216);   //  8 MB
  unsigned short* Kb     = (unsigned short*)(ws + 25165824);   //  8 MB
  unsigned short* Vtb    = (unsigned short*)(ws + 33554432);   //  8 MB
  unsigned short* aob    = (unsigned short*)(ws + 41943040);   //  8 MB

  k_cvt<<<8192, 256, 0, stream>>>(x, w_qkv, w_proj, xb, wqkvb, wprojb);

  k_gemm_qkv<<<dim3(24, 32), 256, 0, stream>>>(xb, wqkvb, b_qkv, fcos, fsin,
                                               Qb, Kb, Vtb);

  k_attn<<<256, 512, 0, stream>>>(Qb, Kb, Vtb, aob);

  k_gemm_proj<<<dim3(16, 64), 256, 0, stream>>>(aob, wprojb, b_proj, out);
}